// Round 3
// baseline (563.688 us; speedup 1.0000x reference)
//
#include <hip/hip_runtime.h>
#include <hip/hip_bf16.h>

// ---------- types ----------
typedef __attribute__((ext_vector_type(8))) __bf16 bf16x8;
typedef __attribute__((ext_vector_type(2))) __bf16 bf16x2;
typedef __attribute__((ext_vector_type(4))) float f32x4;

#define T_SEQ 2048
#define C_DIM 2048
#define QKV_DIM 3072
#define NKV 4
#define HD 128

#define AS1 __attribute__((address_space(1)))
#define AS3 __attribute__((address_space(3)))

__device__ __forceinline__ unsigned short f2bf(float x) {
    __hip_bfloat16 h = __float2bfloat16(x);
    return __builtin_bit_cast(unsigned short, h);
}
__device__ __forceinline__ float bf2f(unsigned short u) {
    unsigned int i = ((unsigned int)u) << 16;
    return __builtin_bit_cast(float, i);
}
// packed bf16 conversion: single v_cvt_pk_bf16_f32 on gfx950 if available
__device__ __forceinline__ unsigned int pkbf(float lo, float hi) {
#if __has_builtin(__builtin_amdgcn_cvt_pk_bf16_f32)
    bf16x2 r = __builtin_amdgcn_cvt_pk_bf16_f32(lo, hi);
    return __builtin_bit_cast(unsigned int, r);
#else
    return ((unsigned int)f2bf(hi) << 16) | (unsigned int)f2bf(lo);
#endif
}
__device__ __forceinline__ f32x4 mfma16(bf16x8 a, bf16x8 b, f32x4 c) {
    return __builtin_amdgcn_mfma_f32_16x16x32_bf16(a, b, c, 0, 0, 0);
}
__device__ __forceinline__ void gload_lds16(const void* g, void* l) {
    __builtin_amdgcn_global_load_lds((const AS1 unsigned int*)g,
                                     (AS3 unsigned int*)l, 16, 0, 0);
}

// ---------- elementwise cast x -> bf16 ----------
__global__ __launch_bounds__(256) void cast_f32_to_bf16(
        const float* __restrict__ in, unsigned short* __restrict__ out, int n4) {
    int i = blockIdx.x * 256 + threadIdx.x;
    if (i >= n4) return;
    float4 v = ((const float4*)in)[i];
    uint2 o;
    o.x = pkbf(v.x, v.y);
    o.y = pkbf(v.z, v.w);
    ((uint2*)out)[i] = o;
}

// ---------- cast+transpose fp32 [rows][cols] -> bf16 [cols][rows] ----------
__global__ __launch_bounds__(256) void transpose_cast_f32_bf16(
        const float* __restrict__ in, unsigned short* __restrict__ out,
        int rows, int cols) {
    __shared__ float tile[32][33];
    int c0 = blockIdx.x * 32, r0 = blockIdx.y * 32;
    int tx = threadIdx.x, ty = threadIdx.y;
    #pragma unroll
    for (int i = 0; i < 4; i++)
        tile[ty + 8 * i][tx] = in[(size_t)(r0 + ty + 8 * i) * cols + c0 + tx];
    __syncthreads();
    #pragma unroll
    for (int i = 0; i < 4; i++)
        out[(size_t)(c0 + ty + 8 * i) * rows + r0 + tx] = f2bf(tile[tx][ty + 8 * i]);
}

// ---------- transpose V cols of qkv -> vt[b][kv*128+d][t] ----------
__global__ __launch_bounds__(256) void transpose_v(
        const unsigned short* __restrict__ qkv, unsigned short* __restrict__ vt) {
    __shared__ unsigned short tile[32][33];
    int c0 = blockIdx.x * 32;   // d-col 0..511
    int r0 = blockIdx.y * 32;   // row (b*T+t) 0..4095
    int tx = threadIdx.x, ty = threadIdx.y;
    #pragma unroll
    for (int i = 0; i < 4; i++)
        tile[ty + 8 * i][tx] =
            qkv[(size_t)(r0 + ty + 8 * i) * QKV_DIM + 2560 + c0 + tx];
    __syncthreads();
    #pragma unroll
    for (int i = 0; i < 4; i++) {
        int d = c0 + ty + 8 * i;
        int r = r0 + tx;
        int b = r >> 11, t = r & (T_SEQ - 1);
        vt[(size_t)b * 512 * T_SEQ + (size_t)d * T_SEQ + t] = tile[tx][ty + 8 * i];
    }
}

// ---------- YaRN cos/sin table: tab[t*64+i] = (cos, sin) ----------
__global__ __launch_bounds__(256) void yarn_tab_kernel(float2* __restrict__ tab) {
    int idx = blockIdx.x * 256 + threadIdx.x;   // t*64 + i, t < 2048
    int t = idx >> 6, i = idx & 63;
    float inv = 0.25f * exp2f(-(float)i * (13.287712379549449f / 64.0f));
    float ang = (float)t * inv;
    float s, c;
    __sincosf(ang, &s, &c);
    tab[idx] = make_float2(c, s);
}

// ---------- RoPE via table, 4B vectorized ----------
__global__ __launch_bounds__(256) void rope_kernel(
        unsigned short* __restrict__ qkv, const float2* __restrict__ tab) {
    int row = blockIdx.x;            // b*T + t
    int t = row & (T_SEQ - 1);
    const float2* tb = tab + t * 64;
    for (int p = threadIdx.x; p < 1280; p += 256) {  // 20 heads * 64 pairs
        int head = p >> 6, i = p & 63;
        float2 cs = tb[i];
        size_t idx = (size_t)row * QKV_DIM + head * 128 + 2 * i;
        unsigned int u = *(const unsigned int*)(qkv + idx);
        float e = bf2f((unsigned short)(u & 0xffff));
        float o = bf2f((unsigned short)(u >> 16));
        *(unsigned int*)(qkv + idx) = pkbf(e * cs.x - o * cs.y, o * cs.x + e * cs.y);
    }
}

// ---------- GEMM (m97 structure): C[M,N] = A[M,K] @ Bt[N,K]^T ----------
template <int OUT_BF16>
__global__ __launch_bounds__(256) void gemm_bt(
        const unsigned short* __restrict__ A, const unsigned short* __restrict__ Bt,
        void* __restrict__ Cout, int M, int N, int K) {
    __shared__ __align__(16) unsigned short As[128 * 32];
    __shared__ __align__(16) unsigned short Bs[128 * 32];
    int tid = threadIdx.x;
    int m0 = blockIdx.y * 128, n0 = blockIdx.x * 128;
    int wave = tid >> 6, lane = tid & 63;
    int wm = (wave & 1) * 64, wn = (wave >> 1) * 64;
    int l15 = lane & 15, quad = lane >> 4;
    int lrow = lane >> 2, lcol = (lane & 3) * 8;

    f32x4 zf = {0.f, 0.f, 0.f, 0.f};
    f32x4 acc[4][4];
    #pragma unroll
    for (int i = 0; i < 4; i++)
        #pragma unroll
        for (int j = 0; j < 4; j++) acc[i][j] = zf;

    int ca = wave * 2;
    const unsigned short* gA = A + (size_t)(m0 + ca * 16 + lrow) * K + lcol;
    const unsigned short* gB = Bt + (size_t)(n0 + ca * 16 + lrow) * K + lcol;

    for (int k0 = 0; k0 < K; k0 += 32) {
        gload_lds16(gA + k0, &As[ca * 512]);
        gload_lds16(gA + k0 + 16 * (size_t)K, &As[ca * 512 + 512]);
        gload_lds16(gB + k0, &Bs[ca * 512]);
        gload_lds16(gB + k0 + 16 * (size_t)K, &Bs[ca * 512 + 512]);
        __syncthreads();
        bf16x8 af[4], bfr[4];
        #pragma unroll
        for (int i = 0; i < 4; i++)
            af[i] = *(const bf16x8*)&As[(wm + i * 16 + l15) * 32 + quad * 8];
        #pragma unroll
        for (int i = 0; i < 4; i++)
            bfr[i] = *(const bf16x8*)&Bs[(wn + i * 16 + l15) * 32 + quad * 8];
        #pragma unroll
        for (int mi = 0; mi < 4; mi++)
            #pragma unroll
            for (int ni = 0; ni < 4; ni++)
                acc[mi][ni] = mfma16(af[mi], bfr[ni], acc[mi][ni]);
        __syncthreads();
    }
    #pragma unroll
    for (int mi = 0; mi < 4; mi++)
        #pragma unroll
        for (int ni = 0; ni < 4; ni++) {
            int row = m0 + wm + mi * 16 + quad * 4;
            int col = n0 + wn + ni * 16 + l15;
            #pragma unroll
            for (int r = 0; r < 4; r++) {
                float v = acc[mi][ni][r];
                if (OUT_BF16)
                    ((unsigned short*)Cout)[(size_t)(row + r) * N + col] = f2bf(v);
                else
                    ((float*)Cout)[(size_t)(row + r) * N + col] = v;
            }
        }
}

// ---------- flash attention: block = (b,h,qt), 4 waves split the key range ----------
// No-max softmax (scores softcapped to +-50): partial (O,l) over disjoint key
// ranges are directly additive -> cross-wave LDS reduction at the end.
__global__ __launch_bounds__(256) void attn_kernel(
        const unsigned short* __restrict__ qkv, const unsigned short* __restrict__ vt,
        unsigned short* __restrict__ attn_out) {
    __shared__ __align__(16) f32x4 red[8][4][64];      // [dd][wave][lane], 32 KB
    __shared__ float lred[4][64];                       // 1 KB
    __shared__ __align__(16) unsigned int pTb[4][16 * 20];  // per-wave P^T, 5 KB

    int bid = blockIdx.x;
    int qt = bid & 127, h = (bid >> 7) & 15, b = bid >> 11;
    int tid = threadIdx.x;
    int w = tid >> 6, lane = tid & 63;
    int l15 = lane & 15, quad = lane >> 4;
    int kv = h >> 2;
    unsigned int* pT = pTb[w];
    f32x4 zf = {0.f, 0.f, 0.f, 0.f};

    // Q B-frag: Q[qrow=l15][k=c*32+quad*8+j]
    const unsigned short* qp =
        qkv + (size_t)(b * T_SEQ + qt * 16 + l15) * QKV_DIM + h * HD + quad * 8;
    bf16x8 aq[4];
    #pragma unroll
    for (int c = 0; c < 4; c++) aq[c] = *(const bf16x8*)(qp + c * 32);

    const unsigned short* kbase = qkv + (size_t)b * T_SEQ * QKV_DIM + 2048 + kv * HD;
    const unsigned short* vbase = vt + (size_t)(b * NKV + kv) * HD * T_SEQ;

    f32x4 oacc[8];
    #pragma unroll
    for (int d = 0; d < 8; d++) oacc[d] = zf;
    float lsum = 0.f;

    int qglob = qt * 16 + l15;
    int kmax = qt * 16 + 16;
    // fused softcap+exp: p = e^50 * exp2(-144.2695/(e+1)), e = exp2(s*K1)
    const float K1 = 0.0051006972f;        // (1/sqrt(128)) * (2/50) * log2(e)
    const float K2 = -144.26950408889634f; // -100 * log2(e)
    const float CC = 5.184705528587072e21f; // e^50

    for (int k0 = w * 32; k0 < kmax; k0 += 128) {
        // S^T = K.Q^T : two 16-key tiles
        f32x4 s0 = zf, s1 = zf;
        const unsigned short* kp0 = kbase + (size_t)(k0 + l15) * QKV_DIM + quad * 8;
        const unsigned short* kp1 = kp0 + (size_t)16 * QKV_DIM;
        #pragma unroll
        for (int c = 0; c < 4; c++) {
            bf16x8 a0 = *(const bf16x8*)(kp0 + c * 32);
            bf16x8 a1 = *(const bf16x8*)(kp1 + c * 32);
            s0 = mfma16(a0, aq[c], s0);
            s1 = mfma16(a1, aq[c], s1);
        }
        float p0[4], p1[4];
        #pragma unroll
        for (int r = 0; r < 4; r++) {
            int key0 = k0 + quad * 4 + r;
            float e0 = exp2f(s0[r] * K1);
            float e1 = exp2f(s1[r] * K1);
            float q0 = CC * exp2f(K2 * __builtin_amdgcn_rcpf(e0 + 1.f));
            float q1 = CC * exp2f(K2 * __builtin_amdgcn_rcpf(e1 + 1.f));
            p0[r] = (key0 <= qglob) ? q0 : 0.f;
            p1[r] = (key0 + 16 <= qglob) ? q1 : 0.f;
            lsum += p0[r] + p1[r];
        }
        // P^T transpose via per-wave LDS (in-order within wave, no barrier)
        unsigned int d0 = pkbf(p0[0], p0[1]), d1 = pkbf(p0[2], p0[3]);
        unsigned int d2 = pkbf(p1[0], p1[1]), d3 = pkbf(p1[2], p1[3]);
        unsigned int* wp = pT + l15 * 20 + quad * 2;
        *(uint2*)wp = make_uint2(d0, d1);
        *(uint2*)(wp + 8) = make_uint2(d2, d3);
        __asm__ volatile("s_waitcnt lgkmcnt(0)" ::: "memory");
        bf16x8 bp = *(const bf16x8*)(pT + l15 * 20 + quad * 4);
        // O^T += V^T . P^T
        const unsigned short* vp = vbase + (size_t)l15 * T_SEQ + k0 + quad * 8;
        #pragma unroll
        for (int dd = 0; dd < 8; dd++) {
            bf16x8 av = *(const bf16x8*)(vp + (size_t)dd * 16 * T_SEQ);
            oacc[dd] = mfma16(av, bp, oacc[dd]);
        }
        __asm__ volatile("" ::: "memory");
    }
    // cross-wave reduction
    lred[w][lane] = lsum;
    #pragma unroll
    for (int dd = 0; dd < 8; dd++) red[dd][w][lane] = oacc[dd];
    __syncthreads();
    float lt = lred[0][lane] + lred[1][lane] + lred[2][lane] + lred[3][lane];
    lt += __shfl_xor(lt, 16);
    lt += __shfl_xor(lt, 32);
    float rl = __builtin_amdgcn_rcpf(lt);
    unsigned short* op = attn_out +
        (size_t)(b * T_SEQ + qt * 16 + l15) * C_DIM + h * HD + quad * 4;
    #pragma unroll
    for (int j = 0; j < 2; j++) {
        int dd = w * 2 + j;
        f32x4 o = red[dd][0][lane];
        o += red[dd][1][lane];
        o += red[dd][2][lane];
        o += red[dd][3][lane];
        unsigned int u0 = pkbf(o[0] * rl, o[1] * rl);
        unsigned int u1 = pkbf(o[2] * rl, o[3] * rl);
        *(uint2*)(op + dd * 16) = make_uint2(u0, u1);
    }
}

extern "C" void kernel_launch(void* const* d_in, const int* in_sizes, int n_in,
                              void* d_out, int out_size, void* d_ws, size_t ws_size,
                              hipStream_t stream) {
    (void)in_sizes; (void)n_in; (void)out_size; (void)ws_size;
    const float* x = (const float*)d_in[0];
    const float* w_qkv = (const float*)d_in[1];
    const float* w_o = (const float*)d_in[2];
    char* ws = (char*)d_ws;

    unsigned short* xbf   = (unsigned short*)(ws);                       // 16 MB
    unsigned short* wqkvT = (unsigned short*)(ws + 16777216);            // 12 MB
    unsigned short* woT   = (unsigned short*)(ws + 29360128);            //  8 MB
    unsigned short* qkv   = (unsigned short*)(ws + 37748736);            // 24 MB
    unsigned short* vt    = (unsigned short*)(ws + 62914560);            //  4 MB -> 64 MB
    float2*         tab   = (float2*)(ws + 62914560);  // overlaps vt: dead before transpose_v
    unsigned short* attn  = xbf;  // xbf dead after gemm1

    cast_f32_to_bf16<<<8192, 256, 0, stream>>>(x, xbf, 2097152);
    transpose_cast_f32_bf16<<<dim3(96, 64), dim3(32, 8), 0, stream>>>(w_qkv, wqkvT, 2048, 3072);
    transpose_cast_f32_bf16<<<dim3(64, 64), dim3(32, 8), 0, stream>>>(w_o, woT, 2048, 2048);
    yarn_tab_kernel<<<512, 256, 0, stream>>>(tab);
    gemm_bt<1><<<dim3(24, 32), 256, 0, stream>>>(xbf, wqkvT, qkv, 4096, 3072, 2048);
    rope_kernel<<<4096, 256, 0, stream>>>(qkv, tab);
    transpose_v<<<dim3(16, 128), dim3(32, 8), 0, stream>>>(qkv, vt);
    attn_kernel<<<4096, 256, 0, stream>>>(qkv, vt, attn);
    gemm_bt<0><<<dim3(16, 32), 256, 0, stream>>>(attn, woT, d_out, 4096, 2048, 2048);
}

// Round 4
// 424.645 us; speedup vs baseline: 1.3274x; 1.3274x over previous
//
#include <hip/hip_runtime.h>
#include <hip/hip_bf16.h>

// ---------- types ----------
typedef __attribute__((ext_vector_type(8))) __bf16 bf16x8;
typedef __attribute__((ext_vector_type(2))) __bf16 bf16x2;
typedef __attribute__((ext_vector_type(4))) float f32x4;

#define T_SEQ 2048
#define C_DIM 2048
#define QKV_DIM 3072
#define NKV 4
#define HD 128

#define AS1 __attribute__((address_space(1)))
#define AS3 __attribute__((address_space(3)))

__device__ __forceinline__ unsigned short f2bf(float x) {
    __hip_bfloat16 h = __float2bfloat16(x);
    return __builtin_bit_cast(unsigned short, h);
}
__device__ __forceinline__ float bf2f(unsigned short u) {
    unsigned int i = ((unsigned int)u) << 16;
    return __builtin_bit_cast(float, i);
}
__device__ __forceinline__ unsigned int pkbf(float lo, float hi) {
#if __has_builtin(__builtin_amdgcn_cvt_pk_bf16_f32)
    bf16x2 r = __builtin_amdgcn_cvt_pk_bf16_f32(lo, hi);
    return __builtin_bit_cast(unsigned int, r);
#else
    return ((unsigned int)f2bf(hi) << 16) | (unsigned int)f2bf(lo);
#endif
}
__device__ __forceinline__ f32x4 mfma16(bf16x8 a, bf16x8 b, f32x4 c) {
    return __builtin_amdgcn_mfma_f32_16x16x32_bf16(a, b, c, 0, 0, 0);
}
__device__ __forceinline__ void gload_lds16(const void* g, void* l) {
    __builtin_amdgcn_global_load_lds((const AS1 unsigned int*)g,
                                     (AS3 unsigned int*)l, 16, 0, 0);
}

// ---------- elementwise cast x -> bf16 ----------
__global__ __launch_bounds__(256) void cast_f32_to_bf16(
        const float* __restrict__ in, unsigned short* __restrict__ out, int n4) {
    int i = blockIdx.x * 256 + threadIdx.x;
    if (i >= n4) return;
    float4 v = ((const float4*)in)[i];
    uint2 o;
    o.x = pkbf(v.x, v.y);
    o.y = pkbf(v.z, v.w);
    ((uint2*)out)[i] = o;
}

// ---------- cast+transpose fp32 [rows][cols] -> bf16 [cols][rows] ----------
__global__ __launch_bounds__(256) void transpose_cast_f32_bf16(
        const float* __restrict__ in, unsigned short* __restrict__ out,
        int rows, int cols) {
    __shared__ float tile[32][33];
    int c0 = blockIdx.x * 32, r0 = blockIdx.y * 32;
    int tx = threadIdx.x, ty = threadIdx.y;
    #pragma unroll
    for (int i = 0; i < 4; i++)
        tile[ty + 8 * i][tx] = in[(size_t)(r0 + ty + 8 * i) * cols + c0 + tx];
    __syncthreads();
    #pragma unroll
    for (int i = 0; i < 4; i++)
        out[(size_t)(c0 + ty + 8 * i) * rows + r0 + tx] = f2bf(tile[tx][ty + 8 * i]);
}

// ---------- transpose V cols of qkv -> tiled vt[b][kv][t/32][d 0..127][t%32] ----------
__global__ __launch_bounds__(256) void transpose_v(
        const unsigned short* __restrict__ qkv, unsigned short* __restrict__ vt) {
    __shared__ unsigned short tile[32][33];
    int c0 = blockIdx.x * 32;   // d-col 0..511
    int r0 = blockIdx.y * 32;   // row (b*T+t) 0..4095
    int tx = threadIdx.x, ty = threadIdx.y;
    #pragma unroll
    for (int i = 0; i < 4; i++)
        tile[ty + 8 * i][tx] =
            qkv[(size_t)(r0 + ty + 8 * i) * QKV_DIM + 2560 + c0 + tx];
    __syncthreads();
    #pragma unroll
    for (int i = 0; i < 4; i++) {
        int dcol = c0 + ty + 8 * i;
        int kv = dcol >> 7, d = dcol & 127;
        int r = r0 + tx;
        int b = r >> 11, t = r & (T_SEQ - 1);
        vt[(size_t)((b * NKV + kv) * 64 + (t >> 5)) * 4096 + d * 32 + (t & 31)] =
            tile[tx][ty + 8 * i];
    }
}

// ---------- YaRN cos/sin table ----------
__global__ __launch_bounds__(256) void yarn_tab_kernel(float2* __restrict__ tab) {
    int idx = blockIdx.x * 256 + threadIdx.x;   // t*64 + i
    int t = idx >> 6, i = idx & 63;
    float inv = 0.25f * exp2f(-(float)i * (13.287712379549449f / 64.0f));
    float ang = (float)t * inv;
    float s, c;
    __sincosf(ang, &s, &c);
    tab[idx] = make_float2(c, s);
}

// ---------- RoPE via table ----------
__global__ __launch_bounds__(256) void rope_kernel(
        unsigned short* __restrict__ qkv, const float2* __restrict__ tab) {
    int row = blockIdx.x;
    int t = row & (T_SEQ - 1);
    const float2* tb = tab + t * 64;
    for (int p = threadIdx.x; p < 1280; p += 256) {
        int head = p >> 6, i = p & 63;
        float2 cs = tb[i];
        size_t idx = (size_t)row * QKV_DIM + head * 128 + 2 * i;
        unsigned int u = *(const unsigned int*)(qkv + idx);
        float e = bf2f((unsigned short)(u & 0xffff));
        float o = bf2f((unsigned short)(u >> 16));
        *(unsigned int*)(qkv + idx) = pkbf(e * cs.x - o * cs.y, o * cs.x + e * cs.y);
    }
}

// ---------- GEMM (m97 structure): C[M,N] = A[M,K] @ Bt[N,K]^T ----------
template <int OUT_BF16>
__global__ __launch_bounds__(256) void gemm_bt(
        const unsigned short* __restrict__ A, const unsigned short* __restrict__ Bt,
        void* __restrict__ Cout, int M, int N, int K) {
    __shared__ __align__(16) unsigned short As[128 * 32];
    __shared__ __align__(16) unsigned short Bs[128 * 32];
    int tid = threadIdx.x;
    int m0 = blockIdx.y * 128, n0 = blockIdx.x * 128;
    int wave = tid >> 6, lane = tid & 63;
    int wm = (wave & 1) * 64, wn = (wave >> 1) * 64;
    int l15 = lane & 15, quad = lane >> 4;
    int lrow = lane >> 2, lcol = (lane & 3) * 8;

    f32x4 zf = {0.f, 0.f, 0.f, 0.f};
    f32x4 acc[4][4];
    #pragma unroll
    for (int i = 0; i < 4; i++)
        #pragma unroll
        for (int j = 0; j < 4; j++) acc[i][j] = zf;

    int ca = wave * 2;
    const unsigned short* gA = A + (size_t)(m0 + ca * 16 + lrow) * K + lcol;
    const unsigned short* gB = Bt + (size_t)(n0 + ca * 16 + lrow) * K + lcol;

    for (int k0 = 0; k0 < K; k0 += 32) {
        gload_lds16(gA + k0, &As[ca * 512]);
        gload_lds16(gA + k0 + 16 * (size_t)K, &As[ca * 512 + 512]);
        gload_lds16(gB + k0, &Bs[ca * 512]);
        gload_lds16(gB + k0 + 16 * (size_t)K, &Bs[ca * 512 + 512]);
        __syncthreads();
        bf16x8 af[4], bfr[4];
        #pragma unroll
        for (int i = 0; i < 4; i++)
            af[i] = *(const bf16x8*)&As[(wm + i * 16 + l15) * 32 + quad * 8];
        #pragma unroll
        for (int i = 0; i < 4; i++)
            bfr[i] = *(const bf16x8*)&Bs[(wn + i * 16 + l15) * 32 + quad * 8];
        #pragma unroll
        for (int mi = 0; mi < 4; mi++)
            #pragma unroll
            for (int ni = 0; ni < 4; ni++)
                acc[mi][ni] = mfma16(af[mi], bfr[ni], acc[mi][ni]);
        __syncthreads();
    }
    #pragma unroll
    for (int mi = 0; mi < 4; mi++)
        #pragma unroll
        for (int ni = 0; ni < 4; ni++) {
            int row = m0 + wm + mi * 16 + quad * 4;
            int col = n0 + wn + ni * 16 + l15;
            #pragma unroll
            for (int r = 0; r < 4; r++) {
                float v = acc[mi][ni][r];
                if (OUT_BF16)
                    ((unsigned short*)Cout)[(size_t)(row + r) * N + col] = f2bf(v);
                else
                    ((float*)Cout)[(size_t)(row + r) * N + col] = v;
            }
        }
}

// ---------- flash attention: 1 wave per q-tile pair, software-pipelined ----------
__device__ __forceinline__ void attn_one(
        const unsigned short* __restrict__ qkv, const unsigned short* __restrict__ vt,
        unsigned short* __restrict__ attn_out, unsigned int* __restrict__ pT,
        int b, int h, int qt, int lane) {
    int l15 = lane & 15, quad = lane >> 4;
    int kv = h >> 2;
    f32x4 zf = {0.f, 0.f, 0.f, 0.f};

    // Q B-frag: Q[qrow=l15][k=c*32+quad*8+j]
    const unsigned short* qp =
        qkv + (size_t)(b * T_SEQ + qt * 16 + l15) * QKV_DIM + h * HD + quad * 8;
    bf16x8 aq[4];
    #pragma unroll
    for (int c = 0; c < 4; c++) aq[c] = *(const bf16x8*)(qp + c * 32);

    const unsigned short* kbase = qkv + (size_t)b * T_SEQ * QKV_DIM + 2048 + kv * HD;
    const unsigned short* vbase = vt + (size_t)(b * NKV + kv) * 64 * 4096;
    const unsigned short* pk0 = kbase + (size_t)l15 * QKV_DIM + quad * 8;
    const unsigned short* pk1 = pk0 + (size_t)16 * QKV_DIM;
    const unsigned short* pv0 = vbase + l15 * 32 + quad * 8;
    const unsigned short* pv1 = pv0 + 2048;

    f32x4 oacc[8];
    #pragma unroll
    for (int d = 0; d < 8; d++) oacc[d] = zf;
    float lsum = 0.f;

    int qglob = qt * 16 + l15;
    int n = (qt >> 1) + 1;   // number of 32-key tiles

    const float K1 = 0.0051006972f;         // invsqrt(128)*(2/50)*log2(e)
    const float K2 = -144.26950408889634f;  // -100*log2(e)
    const float K3 = 72.13475204444817f;    // 50*log2(e)

    bf16x8 KA[8], KB[8];

    auto loadK = [&](bf16x8* K, int t) {
        const unsigned short* a = pk0 + (size_t)t * 32 * QKV_DIM;
        const unsigned short* b_ = pk1 + (size_t)t * 32 * QKV_DIM;
        #pragma unroll
        for (int c = 0; c < 4; c++) {
            K[c] = *(const bf16x8*)(a + c * 32);
            K[4 + c] = *(const bf16x8*)(b_ + c * 32);
        }
    };

    auto step = [&](const bf16x8* K, unsigned int* buf, bool masked, int t,
                    bf16x8* Kpre, int tpre, bool do_pre) {
        // V loads first (oldest vmem of this tile)
        const unsigned short* v0 = pv0 + (size_t)t * 4096;
        const unsigned short* v1 = pv1 + (size_t)t * 4096;
        bf16x8 Vv[8];
        #pragma unroll
        for (int dd = 0; dd < 4; dd++) {
            Vv[dd] = *(const bf16x8*)(v0 + dd * 512);
            Vv[4 + dd] = *(const bf16x8*)(v1 + dd * 512);
        }
        // prefetch next K (stays in flight across PV's vmcnt wait)
        if (do_pre) loadK(Kpre, tpre);
        // S^T = K.Q^T
        f32x4 s0 = zf, s1 = zf;
        #pragma unroll
        for (int c = 0; c < 4; c++) {
            s0 = mfma16(K[c], aq[c], s0);
            s1 = mfma16(K[4 + c], aq[c], s1);
        }
        float p0[4], p1[4];
        int kb = t * 32 + quad * 4;
        #pragma unroll
        for (int r = 0; r < 4; r++) {
            float e0 = exp2f(s0[r] * K1);
            float e1 = exp2f(s1[r] * K1);
            float q0 = exp2f(fmaf(K2, __builtin_amdgcn_rcpf(e0 + 1.f), K3));
            float q1 = exp2f(fmaf(K2, __builtin_amdgcn_rcpf(e1 + 1.f), K3));
            if (masked) {
                q0 = (kb + r <= qglob) ? q0 : 0.f;
                q1 = (kb + 16 + r <= qglob) ? q1 : 0.f;
            }
            p0[r] = q0; p1[r] = q1;
            lsum += q0 + q1;
        }
        // P^T transpose via LDS (single wave, in-order)
        unsigned int d0 = pkbf(p0[0], p0[1]), d1 = pkbf(p0[2], p0[3]);
        unsigned int d2 = pkbf(p1[0], p1[1]), d3 = pkbf(p1[2], p1[3]);
        unsigned int* wp = buf + l15 * 20 + quad * 2;
        *(uint2*)wp = make_uint2(d0, d1);
        *(uint2*)(wp + 8) = make_uint2(d2, d3);
        __asm__ volatile("s_waitcnt lgkmcnt(0)" ::: "memory");
        bf16x8 bp = *(const bf16x8*)(buf + l15 * 20 + quad * 4);
        // O^T += V^T . P^T
        #pragma unroll
        for (int dd = 0; dd < 8; dd++) oacc[dd] = mfma16(Vv[dd], bp, oacc[dd]);
    };

    loadK(KA, 0);
    int t = 0;
    while (true) {
        bool last = (t == n - 1);
        step(KA, pT, last, t, KB, t + 1, !last);
        if (last) break;
        t++;
        last = (t == n - 1);
        step(KB, pT + 320, last, t, KA, t + 1, !last);
        if (last) break;
        t++;
    }

    float l = lsum;
    l += __shfl_xor(l, 16);
    l += __shfl_xor(l, 32);
    float rl = __builtin_amdgcn_rcpf(l);
    unsigned short* op = attn_out +
        (size_t)(b * T_SEQ + qt * 16 + l15) * C_DIM + h * HD + quad * 4;
    #pragma unroll
    for (int dd = 0; dd < 8; dd++) {
        unsigned int u0 = pkbf(oacc[dd][0] * rl, oacc[dd][1] * rl);
        unsigned int u1 = pkbf(oacc[dd][2] * rl, oacc[dd][3] * rl);
        *(uint2*)(op + dd * 16) = make_uint2(u0, u1);
    }
}

__global__ __launch_bounds__(64, 2) void attn_kernel(
        const unsigned short* __restrict__ qkv, const unsigned short* __restrict__ vt,
        unsigned short* __restrict__ attn_out) {
    __shared__ __align__(16) unsigned int pT[2 * 320];
    int bid = blockIdx.x;
    int j = bid & 63, h = (bid >> 6) & 15, b = bid >> 10;
    int lane = threadIdx.x;
    attn_one(qkv, vt, attn_out, pT, b, h, j, lane);        // short tile
    attn_one(qkv, vt, attn_out, pT, b, h, 127 - j, lane);  // long tile: sum = 65
}

extern "C" void kernel_launch(void* const* d_in, const int* in_sizes, int n_in,
                              void* d_out, int out_size, void* d_ws, size_t ws_size,
                              hipStream_t stream) {
    (void)in_sizes; (void)n_in; (void)out_size; (void)ws_size;
    const float* x = (const float*)d_in[0];
    const float* w_qkv = (const float*)d_in[1];
    const float* w_o = (const float*)d_in[2];
    char* ws = (char*)d_ws;

    unsigned short* xbf   = (unsigned short*)(ws);                       // 16 MB
    unsigned short* wqkvT = (unsigned short*)(ws + 16777216);            // 12 MB
    unsigned short* woT   = (unsigned short*)(ws + 29360128);            //  8 MB
    unsigned short* qkv   = (unsigned short*)(ws + 37748736);            // 24 MB
    unsigned short* vt    = (unsigned short*)(ws + 62914560);            //  4 MB -> 64 MB
    float2*         tab   = (float2*)(ws + 62914560);  // overlaps vt: dead before transpose_v
    unsigned short* attn  = xbf;  // xbf dead after gemm1

    cast_f32_to_bf16<<<8192, 256, 0, stream>>>(x, xbf, 2097152);
    transpose_cast_f32_bf16<<<dim3(96, 64), dim3(32, 8), 0, stream>>>(w_qkv, wqkvT, 2048, 3072);
    transpose_cast_f32_bf16<<<dim3(64, 64), dim3(32, 8), 0, stream>>>(w_o, woT, 2048, 2048);
    yarn_tab_kernel<<<512, 256, 0, stream>>>(tab);
    gemm_bt<1><<<dim3(24, 32), 256, 0, stream>>>(xbf, wqkvT, qkv, 4096, 3072, 2048);
    rope_kernel<<<4096, 256, 0, stream>>>(qkv, tab);
    transpose_v<<<dim3(16, 128), dim3(32, 8), 0, stream>>>(qkv, vt);
    attn_kernel<<<2048, 64, 0, stream>>>(qkv, vt, attn);
    gemm_bt<0><<<dim3(16, 32), 256, 0, stream>>>(attn, woT, d_out, 4096, 2048, 2048);
}